// Round 9
// baseline (161.384 us; speedup 1.0000x reference)
//
#include <hip/hip_runtime.h>
#include <hip/hip_bf16.h>
#include <stdint.h>

typedef __bf16 bf16x8 __attribute__((ext_vector_type(8)));
typedef float  f32x16 __attribute__((ext_vector_type(16)));
typedef float  f32x4  __attribute__((ext_vector_type(4)));

static constexpr int Bz = 2, Nn = 4096, Ee = 4, Dd = 64, ADim = 32;
static constexpr int Mm = Nn * Ee;        // 16384 reduction dim
static constexpr int KSEG = 2;            // K-segments
static constexpr int KLEN = Mm / KSEG;    // 8192 k per segment
static constexpr int NT = Bz * Nn / 32;   // 256 output row-tiles
static constexpr size_t SEGSTRIDE = (size_t)NT * 32 * 64;  // floats per kseg partial
static constexpr int PHK = 256;           // k per phase (1 KB/row granule)
static constexpr int NPH = KLEN / PHK;    // 32 phases

__device__ __forceinline__ bf16x8 cvt8(float4 a, float4 b) {
  bf16x8 r;
  r[0] = (__bf16)a.x; r[1] = (__bf16)a.y; r[2] = (__bf16)a.z; r[3] = (__bf16)a.w;
  r[4] = (__bf16)b.x; r[5] = (__bf16)b.y; r[6] = (__bf16)b.z; r[7] = (__bf16)b.w;
  return r;
}
__device__ __forceinline__ bf16x8 cvt8v(f32x4 a, f32x4 b) {
  bf16x8 r;
  r[0] = (__bf16)a[0]; r[1] = (__bf16)a[1]; r[2] = (__bf16)a[2]; r[3] = (__bf16)a[3];
  r[4] = (__bf16)b[0]; r[5] = (__bf16)b[1]; r[6] = (__bf16)b[2]; r[7] = (__bf16)b[3];
  return r;
}
__device__ __forceinline__ f32x16 zero16() {
  f32x16 z;
#pragma unroll
  for (int i = 0; i < 16; ++i) z[i] = 0.f;
  return z;
}
__device__ __forceinline__ f32x16 mm(bf16x8 a, bf16x8 b, f32x16 c) {
  return __builtin_amdgcn_mfma_f32_32x32x16_bf16(a, b, c, 0, 0, 0);
}
__device__ __forceinline__ float sigm(float x) { return 1.f / (1.f + __expf(-x)); }
__device__ __forceinline__ float tanh_fast(float x) {
  float e = __expf(2.f * x);
  return 1.f - 2.f / (e + 1.f);
}
__device__ __forceinline__ void async_lds16(const void* g, void* l) {
  __builtin_amdgcn_global_load_lds(
      (const __attribute__((address_space(1))) uint32_t*)g,
      (__attribute__((address_space(3))) uint32_t*)l, 16, 0, 0);
}

// -------- Kernel 0: pack GRU/head weights into bf16 MFMA B-fragments.
__global__ __launch_bounds__(64) void k_pack(
    const float* __restrict__ Wr, const float* __restrict__ Wz,
    const float* __restrict__ Wh, const float* __restrict__ Wo1,
    __bf16* __restrict__ Wp) {
  const int f = blockIdx.x, l = threadIdx.x;
  const int r31 = l & 31, h = l >> 5;
  const float* W; int L, fl;
  if (f < 16)      { W = Wr;  L = 128; fl = f; }
  else if (f < 32) { W = Wz;  L = 128; fl = f - 16; }
  else if (f < 48) { W = Wh;  L = 128; fl = f - 32; }
  else             { W = Wo1; L = 96;  fl = f - 48; }
  const int ks = fl >> 1, oh = fl & 1;
  const float* src = W + (size_t)(32 * oh + r31) * L + 16 * ks + 8 * h;
  float4 s0 = *reinterpret_cast<const float4*>(src);
  float4 s1 = *reinterpret_cast<const float4*>(src + 4);
  *reinterpret_cast<bf16x8*>(Wp + ((size_t)f * 64 + l) * 8) = cvt8(s0, s1);
}

// -------- Kernel 1: Bt[b][d][e*N+n] = sum_d' W_in[e][d][d'] * prop[b][n][d'] + b_in[e][d]
__global__ __launch_bounds__(256) void k_build_bt(
    const float* __restrict__ prop, const float* __restrict__ Win,
    const float* __restrict__ bin, __bf16* __restrict__ Bt) {
  const int nchunk = blockIdx.x;
  const int e = blockIdx.y, b = blockIdx.z;
  const int tid = threadIdx.x;
  const int w = tid >> 6, l = tid & 63;
  const int r31 = l & 31, h = l >> 5;
  const int oh = w & 1, ns = w >> 1;
  const int o_row = oh * 32 + r31;
  const int n_col = nchunk * 64 + ns * 32 + r31;
  const float* wbase = Win + ((size_t)e * 64 + o_row) * 64 + 8 * h;
  const float* pbase = prop + ((size_t)b * Nn + n_col) * 64 + 8 * h;
  f32x16 acc = zero16();
#pragma unroll
  for (int ks = 0; ks < 4; ++ks) {
    float4 w0 = *reinterpret_cast<const float4*>(wbase + 16 * ks);
    float4 w1 = *reinterpret_cast<const float4*>(wbase + 16 * ks + 4);
    float4 p0 = *reinterpret_cast<const float4*>(pbase + 16 * ks);
    float4 p1 = *reinterpret_cast<const float4*>(pbase + 16 * ks + 4);
    acc = mm(cvt8(w0, w1), cvt8(p0, p1), acc);
  }
#pragma unroll
  for (int reg = 0; reg < 16; ++reg) {
    int orow = oh * 32 + (reg & 3) + 8 * (reg >> 2) + 4 * h;
    float v = acc[reg] + bin[e * 64 + orow];
    Bt[((size_t)b * 64 + orow) * Mm + (size_t)e * Nn + n_col] = (__bf16)v;
  }
}

// -------- Kernel 2: split-K GEMM, v4: counted-vmcnt double-buffered pipeline.
// 256 blocks (1/CU), 8 waves = (tile t, col-half q, k-half kh). KSEG=2;
// bid&7 <-> (kseg,bb,g&1) pins each 1 MB Bt slice to one XCD (L2-hot, helped
// by per-block phase rotation). A double-buffered in LDS (128 KB), staged by
// global_load_lds with ONE ROW x 1 KB contiguous per issue. Bt read DIRECT
// from global (L2). Per phase: issue fb(p) -> issue stage(p+1) -> vmcnt(8)
// (keeps stage(p+1) in flight across both barriers; never drains to 0 until
// the last phase) -> barrier -> 8 MFMA -> barrier.
__global__ __launch_bounds__(512, 1) void k_big_gemm(
    const float* __restrict__ A, const __bf16* __restrict__ Bt,
    float* __restrict__ part) {
  __shared__ float at[2][2][32][PHK];    // [buf][tile][row][k] = 128 KB

  const int bid = blockIdx.x;            // 0..255
  const int kseg = bid & 1;
  const int bb   = (bid >> 1) & 1;
  const int g    = bid >> 2;             // 0..63
  const int ph0  = g & (NPH - 1);        // per-block phase rotation
  const int tid = threadIdx.x;
  const int w = tid >> 6, l = tid & 63;
  const int r31 = l & 31, h = l >> 5;
  const int t = w >> 2, q = (w >> 1) & 1, kh = w & 1;
  const size_t kbase = (size_t)kseg * KLEN;
  const int tile = bb * 128 + g * 2 + t;

  const float*  Abase = A + (size_t)bb * Nn * Mm + kbase;
  const __bf16* BtB   = Bt + (size_t)bb * 64 * Mm + kbase;

  // A stage: 8 issues/wave; issue j = one row x 1 KB contiguous.
  // rows rw = 8w+j (0..63): tile t_=rw>>5, row r_=rw&31.
  // XOR pre-swizzle on global source unit (l ^ (r_&7)); read applies same XOR.
#define ISSUE_A(p, buf)                                                     \
  { _Pragma("unroll")                                                       \
    for (int j_ = 0; j_ < 8; ++j_) {                                        \
      const int rw_ = 8 * w + j_;                                           \
      const int t_ = rw_ >> 5, r_ = rw_ & 31;                               \
      const float* src_ = Abase +                                           \
          (size_t)((g * 2 + t_) * 32 + r_) * Mm + (size_t)(p) * PHK +       \
          ((l ^ (r_ & 7)) * 4);                                             \
      async_lds16(src_, (void*)&at[buf][t_][r_][0]);                        \
    } }

  f32x16 acc = zero16();
  ISSUE_A(ph0, 0);

  const int swz = r31 & 7;
  const int ubase = kh * 32;             // this wave's k-half within phase
  const __bf16* fbbase = BtB + (size_t)(32 * q + r31) * Mm + kh * 128 + 8 * h;

  for (int pp = 0; pp < NPH; ++pp) {
    const int pr = (pp + ph0) & (NPH - 1);
    const int bufc = pp & 1;
    // fb(p): 8 direct global loads (L2-resident slice)
    bf16x8 fb[8];
    const __bf16* fbp = fbbase + (size_t)pr * PHK;
#pragma unroll
    for (int s = 0; s < 8; ++s)
      fb[s] = *reinterpret_cast<const bf16x8*>(fbp + 16 * s);
    if (pp + 1 < NPH) {
      const int pn = (pp + 1 + ph0) & (NPH - 1);
      ISSUE_A(pn, bufc ^ 1);
      asm volatile("s_waitcnt vmcnt(8)" ::: "memory");  // stage(p)+fb done; stage(p+1) stays in flight
    } else {
      asm volatile("s_waitcnt vmcnt(0)" ::: "memory");
    }
    __syncthreads();                     // all waves' stage(p) visible
#pragma unroll
    for (int s = 0; s < 8; ++s) {
      const int u0 = ubase + 4 * s + 2 * h;
      f32x4 fa0 = *reinterpret_cast<const f32x4*>(&at[bufc][t][r31][(u0 ^ swz) * 4]);
      f32x4 fa1 = *reinterpret_cast<const f32x4*>(&at[bufc][t][r31][((u0 + 1) ^ swz) * 4]);
      acc = mm(cvt8v(fa0, fa1), fb[s], acc);
    }
    __syncthreads();                     // done reading buf before overwrite
  }
#undef ISSUE_A

  // k-half pair reduction via LDS (reuse buf0 region), then write part.
  float* red = &at[0][0][0][0];
  float* rs = red + (t * 2 + q) * 1024 + l * 16;
  if (kh == 1) {
#pragma unroll
    for (int i = 0; i < 4; ++i) {
      f32x4 v; v[0] = acc[4 * i]; v[1] = acc[4 * i + 1];
      v[2] = acc[4 * i + 2]; v[3] = acc[4 * i + 3];
      *reinterpret_cast<f32x4*>(rs + 4 * i) = v;
    }
  }
  __syncthreads();
  if (kh == 0) {
    float* pb = part + (size_t)kseg * SEGSTRIDE + (size_t)tile * 32 * 64 + 32 * q;
#pragma unroll
    for (int i = 0; i < 4; ++i) {
      f32x4 v = *reinterpret_cast<const f32x4*>(rs + 4 * i);
#pragma unroll
      for (int jj = 0; jj < 4; ++jj) {
        int reg = 4 * i + jj;
        int row = (reg & 3) + 8 * (reg >> 2) + 4 * h;
        pb[row * 64 + r31] = acc[reg] + v[jj];
      }
    }
  }
}

// -------- Kernel 3: fold split-K reduce (2 segs) + GRU gate update + head.
__global__ __launch_bounds__(64) void k_gru(
    const float* __restrict__ part, const float* __restrict__ prop,
    const float* __restrict__ annot, const __bf16* __restrict__ Wp,
    const float* __restrict__ br, const float* __restrict__ bz,
    const float* __restrict__ bh, const float* __restrict__ bo1,
    const float* __restrict__ Wo2, const float* __restrict__ bo2,
    float* __restrict__ out) {
  __shared__ float plds[32][68];
  __shared__ float tlds[32][68];
  const int tile = blockIdx.x;
  const int R0 = tile * 32;
  const int l = threadIdx.x;
  const int r31 = l & 31, h = l >> 5;

  bf16x8 xa[4], xp[4], xan[2];
  {
    const float* pt = part + ((size_t)tile * 32 + r31) * 64 + 8 * h;
    const float* pb = prop + (size_t)(R0 + r31) * 64 + 8 * h;
#pragma unroll
    for (int ks = 0; ks < 4; ++ks) {
      f32x4 s0, s1;
      s0[0] = s0[1] = s0[2] = s0[3] = 0.f;
      s1[0] = s1[1] = s1[2] = s1[3] = 0.f;
#pragma unroll
      for (int seg = 0; seg < KSEG; ++seg) {
        const float* pp = pt + seg * SEGSTRIDE + 16 * ks;
        f32x4 v0 = *reinterpret_cast<const f32x4*>(pp);
        f32x4 v1 = *reinterpret_cast<const f32x4*>(pp + 4);
        s0[0] += v0[0]; s0[1] += v0[1]; s0[2] += v0[2]; s0[3] += v0[3];
        s1[0] += v1[0]; s1[1] += v1[1]; s1[2] += v1[2]; s1[3] += v1[3];
      }
      xa[ks] = cvt8v(s0, s1);
      float4 p0 = *reinterpret_cast<const float4*>(pb + 16 * ks);
      float4 p1 = *reinterpret_cast<const float4*>(pb + 16 * ks + 4);
      xp[ks] = cvt8(p0, p1);
      *reinterpret_cast<float4*>(&plds[r31][16 * ks + 8 * h]) = p0;
      *reinterpret_cast<float4*>(&plds[r31][16 * ks + 8 * h + 4]) = p1;
    }
    const float* anb = annot + (size_t)(R0 + r31) * ADim + 8 * h;
#pragma unroll
    for (int ks = 0; ks < 2; ++ks) {
      float4 a0 = *reinterpret_cast<const float4*>(anb + 16 * ks);
      float4 a1 = *reinterpret_cast<const float4*>(anb + 16 * ks + 4);
      xan[ks] = cvt8(a0, a1);
    }
  }
  __syncthreads();

#define LDWP(base, ks, oh) \
  (*reinterpret_cast<const bf16x8*>(Wp + (((size_t)(base) + (ks) * 2 + (oh)) * 64 + l) * 8))

  f32x16 aR[2] = {zero16(), zero16()}, aZ[2] = {zero16(), zero16()};
#pragma unroll
  for (int ks = 0; ks < 8; ++ks) {
    bf16x8 af = (ks < 4) ? xa[ks] : xp[ks - 4];
#pragma unroll
    for (int oh = 0; oh < 2; ++oh) {
      aR[oh] = mm(af, LDWP(0, ks, oh), aR[oh]);
      aZ[oh] = mm(af, LDWP(16, ks, oh), aZ[oh]);
    }
  }
  const float br_[2] = {br[r31], br[32 + r31]};
  const float bz_[2] = {bz[r31], bz[32 + r31]};
  float propv[2][16], zv[2][16];
#pragma unroll
  for (int oh = 0; oh < 2; ++oh) {
#pragma unroll
    for (int reg = 0; reg < 16; ++reg) {
      int row = (reg & 3) + 8 * (reg >> 2) + 4 * h;
      int o = 32 * oh + r31;
      propv[oh][reg] = plds[row][o];
      float rv = sigm(aR[oh][reg] + br_[oh]);
      zv[oh][reg] = sigm(aZ[oh][reg] + bz_[oh]);
      tlds[row][o] = rv * propv[oh][reg];
    }
  }
  __syncthreads();
  bf16x8 xr[4];
#pragma unroll
  for (int ks = 0; ks < 4; ++ks) {
    float4 t0 = *reinterpret_cast<const float4*>(&tlds[r31][16 * ks + 8 * h]);
    float4 t1 = *reinterpret_cast<const float4*>(&tlds[r31][16 * ks + 8 * h + 4]);
    xr[ks] = cvt8(t0, t1);
  }
  f32x16 aH[2] = {zero16(), zero16()};
#pragma unroll
  for (int ks = 0; ks < 8; ++ks) {
    bf16x8 af = (ks < 4) ? xa[ks] : xr[ks - 4];
#pragma unroll
    for (int oh = 0; oh < 2; ++oh) aH[oh] = mm(af, LDWP(32, ks, oh), aH[oh]);
  }
  __syncthreads();
  const float bh_[2] = {bh[r31], bh[32 + r31]};
#pragma unroll
  for (int oh = 0; oh < 2; ++oh) {
#pragma unroll
    for (int reg = 0; reg < 16; ++reg) {
      int row = (reg & 3) + 8 * (reg >> 2) + 4 * h;
      int o = 32 * oh + r31;
      float hh = tanh_fast(aH[oh][reg] + bh_[oh]);
      float z = zv[oh][reg];
      tlds[row][o] = (1.f - z) * propv[oh][reg] + z * hh;
    }
  }
  __syncthreads();
  bf16x8 xn[4];
#pragma unroll
  for (int ks = 0; ks < 4; ++ks) {
    float4 t0 = *reinterpret_cast<const float4*>(&tlds[r31][16 * ks + 8 * h]);
    float4 t1 = *reinterpret_cast<const float4*>(&tlds[r31][16 * ks + 8 * h + 4]);
    xn[ks] = cvt8(t0, t1);
  }
  f32x16 aO[2] = {zero16(), zero16()};
#pragma unroll
  for (int ks = 0; ks < 6; ++ks) {
    bf16x8 af = (ks < 4) ? xn[ks] : xan[ks - 4];
#pragma unroll
    for (int oh = 0; oh < 2; ++oh) aO[oh] = mm(af, LDWP(48, ks, oh), aO[oh]);
  }
  const float bo1_[2] = {bo1[r31], bo1[32 + r31]};
  const float wo2_[2] = {Wo2[r31], Wo2[32 + r31]};
  const float bo2v = bo2[0];
#pragma unroll
  for (int reg = 0; reg < 16; ++reg) {
    float h0 = tanh_fast(aO[0][reg] + bo1_[0]);
    float h1 = tanh_fast(aO[1][reg] + bo1_[1]);
    float p = h0 * wo2_[0] + h1 * wo2_[1];
#pragma unroll
    for (int mks = 16; mks >= 1; mks >>= 1) p += __shfl_xor(p, mks, 64);
    if (r31 == 0) {
      int row = (reg & 3) + 8 * (reg >> 2) + 4 * h;
      out[R0 + row] = p + bo2v;
    }
  }
#undef LDWP
}

extern "C" void kernel_launch(void* const* d_in, const int* in_sizes, int n_in,
                              void* d_out, int out_size, void* d_ws, size_t ws_size,
                              hipStream_t stream) {
  const float* prop  = (const float*)d_in[0];
  const float* annot = (const float*)d_in[1];
  const float* A     = (const float*)d_in[2];
  const float* Win   = (const float*)d_in[3];
  const float* bin   = (const float*)d_in[4];
  const float* Wr    = (const float*)d_in[5];
  const float* br    = (const float*)d_in[6];
  const float* Wz    = (const float*)d_in[7];
  const float* bz    = (const float*)d_in[8];
  const float* Wh    = (const float*)d_in[9];
  const float* bh    = (const float*)d_in[10];
  const float* Wo1   = (const float*)d_in[11];
  const float* bo1   = (const float*)d_in[12];
  const float* Wo2   = (const float*)d_in[13];
  const float* bo2   = (const float*)d_in[14];
  float* out = (float*)d_out;

  char* ws = (char*)d_ws;
  __bf16* Bt   = (__bf16*)ws;                              // [2][64][16384] bf16 = 4 MB
  float*  part = (float*)(ws + (size_t)4 * 1024 * 1024);   // [2][256][32][64] f32 = 4 MB
  __bf16* Wp   = (__bf16*)(ws + (size_t)12 * 1024 * 1024); // 60 KB

  k_pack<<<dim3(60), 64, 0, stream>>>(Wr, Wz, Wh, Wo1, Wp);
  k_build_bt<<<dim3(Nn / 64, Ee, Bz), 256, 0, stream>>>(prop, Win, bin, Bt);
  k_big_gemm<<<dim3(256), 512, 0, stream>>>(A, Bt, part);
  k_gru<<<dim3(NT), 64, 0, stream>>>(part, prop, annot, Wp,
                                     br, bz, bh, bo1, Wo2, bo2, out);
}

// Round 10
// 134.727 us; speedup vs baseline: 1.1979x; 1.1979x over previous
//
#include <hip/hip_runtime.h>
#include <hip/hip_bf16.h>
#include <stdint.h>

typedef __bf16 bf16x8 __attribute__((ext_vector_type(8)));
typedef float  f32x16 __attribute__((ext_vector_type(16)));
typedef float  f32x4  __attribute__((ext_vector_type(4)));

static constexpr int Bz = 2, Nn = 4096, Ee = 4, Dd = 64, ADim = 32;
static constexpr int Mm = Nn * Ee;        // 16384 reduction dim
static constexpr int KSEG = 8;            // K-segments (== XCDs)
static constexpr int KLEN = Mm / KSEG;    // 2048 k per segment
static constexpr int NT = Bz * Nn / 32;   // 256 output row-tiles
static constexpr size_t SEGSTRIDE = (size_t)NT * 32 * 64;  // floats per kseg partial
static constexpr int PHK = 256;           // k per phase (1 KB/row A granule)
static constexpr int NPH = KLEN / PHK;    // 8 phases

__device__ __forceinline__ bf16x8 cvt8(float4 a, float4 b) {
  bf16x8 r;
  r[0] = (__bf16)a.x; r[1] = (__bf16)a.y; r[2] = (__bf16)a.z; r[3] = (__bf16)a.w;
  r[4] = (__bf16)b.x; r[5] = (__bf16)b.y; r[6] = (__bf16)b.z; r[7] = (__bf16)b.w;
  return r;
}
__device__ __forceinline__ bf16x8 cvt8v(f32x4 a, f32x4 b) {
  bf16x8 r;
  r[0] = (__bf16)a[0]; r[1] = (__bf16)a[1]; r[2] = (__bf16)a[2]; r[3] = (__bf16)a[3];
  r[4] = (__bf16)b[0]; r[5] = (__bf16)b[1]; r[6] = (__bf16)b[2]; r[7] = (__bf16)b[3];
  return r;
}
__device__ __forceinline__ f32x16 zero16() {
  f32x16 z;
#pragma unroll
  for (int i = 0; i < 16; ++i) z[i] = 0.f;
  return z;
}
__device__ __forceinline__ f32x16 mm(bf16x8 a, bf16x8 b, f32x16 c) {
  return __builtin_amdgcn_mfma_f32_32x32x16_bf16(a, b, c, 0, 0, 0);
}
__device__ __forceinline__ float sigm(float x) { return 1.f / (1.f + __expf(-x)); }
__device__ __forceinline__ float tanh_fast(float x) {
  float e = __expf(2.f * x);
  return 1.f - 2.f / (e + 1.f);
}
__device__ __forceinline__ void async_lds16(const void* g, void* l) {
  __builtin_amdgcn_global_load_lds(
      (const __attribute__((address_space(1))) uint32_t*)g,
      (__attribute__((address_space(3))) uint32_t*)l, 16, 0, 0);
}

// -------- Kernel 0: pack GRU/head weights into bf16 MFMA B-fragments.
__global__ __launch_bounds__(64) void k_pack(
    const float* __restrict__ Wr, const float* __restrict__ Wz,
    const float* __restrict__ Wh, const float* __restrict__ Wo1,
    __bf16* __restrict__ Wp) {
  const int f = blockIdx.x, l = threadIdx.x;
  const int r31 = l & 31, h = l >> 5;
  const float* W; int L, fl;
  if (f < 16)      { W = Wr;  L = 128; fl = f; }
  else if (f < 32) { W = Wz;  L = 128; fl = f - 16; }
  else if (f < 48) { W = Wh;  L = 128; fl = f - 32; }
  else             { W = Wo1; L = 96;  fl = f - 48; }
  const int ks = fl >> 1, oh = fl & 1;
  const float* src = W + (size_t)(32 * oh + r31) * L + 16 * ks + 8 * h;
  float4 s0 = *reinterpret_cast<const float4*>(src);
  float4 s1 = *reinterpret_cast<const float4*>(src + 4);
  *reinterpret_cast<bf16x8*>(Wp + ((size_t)f * 64 + l) * 8) = cvt8(s0, s1);
}

// -------- Kernel 1: Bt[b][d][e*N+n] = sum_d' W_in[e][d][d'] * prop[b][n][d'] + b_in[e][d]
__global__ __launch_bounds__(256) void k_build_bt(
    const float* __restrict__ prop, const float* __restrict__ Win,
    const float* __restrict__ bin, __bf16* __restrict__ Bt) {
  const int nchunk = blockIdx.x;
  const int e = blockIdx.y, b = blockIdx.z;
  const int tid = threadIdx.x;
  const int w = tid >> 6, l = tid & 63;
  const int r31 = l & 31, h = l >> 5;
  const int oh = w & 1, ns = w >> 1;
  const int o_row = oh * 32 + r31;
  const int n_col = nchunk * 64 + ns * 32 + r31;
  const float* wbase = Win + ((size_t)e * 64 + o_row) * 64 + 8 * h;
  const float* pbase = prop + ((size_t)b * Nn + n_col) * 64 + 8 * h;
  f32x16 acc = zero16();
#pragma unroll
  for (int ks = 0; ks < 4; ++ks) {
    float4 w0 = *reinterpret_cast<const float4*>(wbase + 16 * ks);
    float4 w1 = *reinterpret_cast<const float4*>(wbase + 16 * ks + 4);
    float4 p0 = *reinterpret_cast<const float4*>(pbase + 16 * ks);
    float4 p1 = *reinterpret_cast<const float4*>(pbase + 16 * ks + 4);
    acc = mm(cvt8(w0, w1), cvt8(p0, p1), acc);
  }
#pragma unroll
  for (int reg = 0; reg < 16; ++reg) {
    int orow = oh * 32 + (reg & 3) + 8 * (reg >> 2) + 4 * h;
    float v = acc[reg] + bin[e * 64 + orow];
    Bt[((size_t)b * 64 + orow) * Mm + (size_t)e * Nn + n_col] = (__bf16)v;
  }
}

// -------- Kernel 2: split-K GEMM, v5: 8 tiles/block, A ping-pong halves,
// Bt register-dbuf, RAW s_barrier + counted vmcnt (no vmcnt(0) in loop).
// 256 blocks (1/CU). kseg = bid&7 (per-XCD Bt slice 256KB x2 batches).
// Block covers 8 tiles (256 rows) as 4 pairs; pair parity -> A half.
// Per phase (PHK=256, 1KB/row issues): compute pair i from half(i&1) while
// staging pair i+2 into the half just freed; Bt(p+1) -> regs during i1,
// ds_write (swizzled) after pair-3 barrier. In-flight never < 8KB/wave.
// Waves: (tp = w>>2, q = (w>>1)&1, kh = w&1); kh-halves LDS-reduced at end.
__global__ __launch_bounds__(512, 1) void k_big_gemm(
    const float* __restrict__ A, const __bf16* __restrict__ Bt,
    float* __restrict__ part) {
  __shared__ float  ahalf[2][64][PHK];   // 2 x 64 KB
  __shared__ __bf16 btl[64][PHK];        // 32 KB  (total 160 KiB)

  const int bid = blockIdx.x;            // 0..255
  const int kseg = bid & 7;
  const int tg   = bid >> 3;             // 0..31
  const int bb   = tg >> 4;
  const int gg   = tg & 15;              // 8-tile group within batch
  const int ph0  = tg & (NPH - 1);       // phase rotation
  const int tid = threadIdx.x;
  const int w = tid >> 6, l = tid & 63;
  const int r31 = l & 31, h = l >> 5;
  const int tp = w >> 2, q = (w >> 1) & 1, kh = w & 1;

  const size_t kbase = (size_t)kseg * KLEN;
  const float*  Ab  = A  + ((size_t)bb * Nn + gg * 256) * Mm + kbase;
  const __bf16* BtB = Bt + (size_t)bb * 64 * Mm + kbase;

  // A stage: pair pi, phase pr -> half hf. 8 issues/wave, 1 row x 1KB each.
#define ISSUE_A(pi, pr, hf)                                                  \
  { _Pragma("unroll")                                                        \
    for (int j_ = 0; j_ < 8; ++j_) {                                         \
      const int rw_ = 8 * w + j_;                                            \
      const float* src_ = Ab + (size_t)((pi) * 64 + rw_) * Mm +              \
                          (size_t)(pr) * PHK + ((l ^ (rw_ & 7)) << 2);       \
      async_lds16(src_, (void*)&ahalf[hf][rw_][0]);                          \
    } }

  // Bt reg load (phase pr): 4 x 1KB coalesced (2 rows x 512B per issue).
  bf16x8 btreg[4];
  const int btrh = l >> 5;               // 0/1 row within pair
  const int btu  = l & 31;               // 16B unit within 512B row
#define LOAD_BT(pr)                                                          \
  { _Pragma("unroll")                                                        \
    for (int j_ = 0; j_ < 4; ++j_) {                                         \
      const int row_ = 8 * w + 2 * j_ + btrh;                                \
      btreg[j_] = *reinterpret_cast<const bf16x8*>(                          \
          BtB + (size_t)row_ * Mm + (size_t)(pr) * PHK + btu * 8);           \
    } }
#define WRITE_BT                                                             \
  { _Pragma("unroll")                                                        \
    for (int j_ = 0; j_ < 4; ++j_) {                                         \
      const int row_ = 8 * w + 2 * j_ + btrh;                                \
      *reinterpret_cast<bf16x8*>(&btl[row_][(btu ^ (row_ & 7)) * 8]) =       \
          btreg[j_];                                                         \
    } }

  const int swz  = r31 & 7;
  const int arow = tp * 32 + r31;
  const int brow = 32 * q + r31;
  f32x16 acc[4] = {zero16(), zero16(), zero16(), zero16()};

#define COMPUTE(pi, hf)                                                      \
  { _Pragma("unroll")                                                        \
    for (int s_ = 0; s_ < 8; ++s_) {                                         \
      const int ua_ = kh * 32 + 4 * s_ + 2 * h;                              \
      f32x4 fa0 = *reinterpret_cast<const f32x4*>(                           \
          &ahalf[hf][arow][((ua_ ^ swz) << 2)]);                             \
      f32x4 fa1 = *reinterpret_cast<const f32x4*>(                           \
          &ahalf[hf][arow][(((ua_ + 1) ^ swz) << 2)]);                       \
      const int ub_ = kh * 16 + 2 * s_ + h;                                  \
      bf16x8 fb = *reinterpret_cast<const bf16x8*>(                          \
          &btl[brow][((ub_ ^ swz) * 8)]);                                    \
      acc[pi] = mm(cvt8v(fa0, fa1), fb, acc[pi]);                            \
    } }

  // ---- prologue: Bt(ph0) via regs; A pair0->half0, pair1->half1
  LOAD_BT(ph0);
  ISSUE_A(0, ph0, 0);
  ISSUE_A(1, ph0, 1);
  asm volatile("s_waitcnt vmcnt(16)" ::: "memory");   // btreg ready
  WRITE_BT;
  asm volatile("s_waitcnt vmcnt(8) lgkmcnt(0)" ::: "memory");  // pair0 in LDS
  __builtin_amdgcn_s_barrier();

  for (int pp = 0; pp < NPH; ++pp) {
    const bool lastp = (pp == NPH - 1);
    const int prc = (pp + ph0) & (NPH - 1);
    const int prn = (pp + 1 + ph0) & (NPH - 1);
    // ---- i=0 : [in flight: pair1(8)]
    COMPUTE(0, 0);
    __builtin_amdgcn_s_barrier();                     // all done reading half0
    ISSUE_A(2, prc, 0);
    asm volatile("s_waitcnt vmcnt(8)" ::: "memory");  // pair1 complete
    __builtin_amdgcn_s_barrier();
    // ---- i=1 : [in flight: pair2(8)]
    COMPUTE(1, 1);
    __builtin_amdgcn_s_barrier();
    if (!lastp) LOAD_BT(prn);                         // +4 (before A for FIFO)
    ISSUE_A(3, prc, 1);
    asm volatile("s_waitcnt vmcnt(8)" ::: "memory");  // pair2 (+Bt regs) done
    __builtin_amdgcn_s_barrier();
    // ---- i=2 : [in flight: pair3(8)]
    COMPUTE(2, 0);
    __builtin_amdgcn_s_barrier();
    if (!lastp) {
      ISSUE_A(0, prn, 0);
      asm volatile("s_waitcnt vmcnt(8)" ::: "memory");  // pair3 complete
    } else {
      asm volatile("s_waitcnt vmcnt(0)" ::: "memory");
    }
    __builtin_amdgcn_s_barrier();
    // ---- i=3 : [in flight: pair0'(8)]
    COMPUTE(3, 1);
    if (!lastp) {
      __builtin_amdgcn_s_barrier();                   // all done reading btl,half1
      WRITE_BT;                                       // btl <- Bt(p+1)
      ISSUE_A(1, prn, 1);
      asm volatile("s_waitcnt vmcnt(8) lgkmcnt(0)" ::: "memory");  // pair0' done
      __builtin_amdgcn_s_barrier();
    }
  }
#undef ISSUE_A
#undef LOAD_BT
#undef WRITE_BT
#undef COMPUTE

  // ---- epilogue: kh-pair reduction via half0 scratch (64KB = 16 slots x 4KB)
  float* scratch = &ahalf[0][0][0];
  float* rs = scratch + ((((w >> 1) * 4) >> 1) * 0);  // (placeholder, computed below)
  (void)rs;
  if (kh == 1) {
#pragma unroll
    for (int i = 0; i < 4; ++i) {
      float* slot = scratch + (size_t)(i * 4 + tp * 2 + q) * 1024 + l * 16;
#pragma unroll
      for (int r = 0; r < 16; r += 4) {
        f32x4 v; v[0] = acc[i][r]; v[1] = acc[i][r + 1];
        v[2] = acc[i][r + 2]; v[3] = acc[i][r + 3];
        *reinterpret_cast<f32x4*>(slot + r) = v;
      }
    }
  }
  __syncthreads();
  if (kh == 0) {
#pragma unroll
    for (int i = 0; i < 4; ++i) {
      const int tile = bb * 128 + gg * 8 + i * 2 + tp;
      float* pb = part + (size_t)kseg * SEGSTRIDE + (size_t)tile * 32 * 64 + 32 * q;
      const float* slot = scratch + (size_t)(i * 4 + tp * 2 + q) * 1024 + l * 16;
#pragma unroll
      for (int reg = 0; reg < 16; ++reg) {
        int row = (reg & 3) + 8 * (reg >> 2) + 4 * h;
        pb[row * 64 + r31] = acc[i][reg] + slot[reg];
      }
    }
  }
}

// -------- Kernel 3: fold split-K reduce (8 segs) + GRU gate update + head.
__global__ __launch_bounds__(64) void k_gru(
    const float* __restrict__ part, const float* __restrict__ prop,
    const float* __restrict__ annot, const __bf16* __restrict__ Wp,
    const float* __restrict__ br, const float* __restrict__ bz,
    const float* __restrict__ bh, const float* __restrict__ bo1,
    const float* __restrict__ Wo2, const float* __restrict__ bo2,
    float* __restrict__ out) {
  __shared__ float plds[32][68];
  __shared__ float tlds[32][68];
  const int tile = blockIdx.x;
  const int R0 = tile * 32;
  const int l = threadIdx.x;
  const int r31 = l & 31, h = l >> 5;

  bf16x8 xa[4], xp[4], xan[2];
  {
    const float* pt = part + ((size_t)tile * 32 + r31) * 64 + 8 * h;
    const float* pb = prop + (size_t)(R0 + r31) * 64 + 8 * h;
#pragma unroll
    for (int ks = 0; ks < 4; ++ks) {
      f32x4 s0, s1;
      s0[0] = s0[1] = s0[2] = s0[3] = 0.f;
      s1[0] = s1[1] = s1[2] = s1[3] = 0.f;
#pragma unroll
      for (int seg = 0; seg < KSEG; ++seg) {
        const float* pp = pt + seg * SEGSTRIDE + 16 * ks;
        f32x4 v0 = *reinterpret_cast<const f32x4*>(pp);
        f32x4 v1 = *reinterpret_cast<const f32x4*>(pp + 4);
        s0[0] += v0[0]; s0[1] += v0[1]; s0[2] += v0[2]; s0[3] += v0[3];
        s1[0] += v1[0]; s1[1] += v1[1]; s1[2] += v1[2]; s1[3] += v1[3];
      }
      xa[ks] = cvt8v(s0, s1);
      float4 p0 = *reinterpret_cast<const float4*>(pb + 16 * ks);
      float4 p1 = *reinterpret_cast<const float4*>(pb + 16 * ks + 4);
      xp[ks] = cvt8(p0, p1);
      *reinterpret_cast<float4*>(&plds[r31][16 * ks + 8 * h]) = p0;
      *reinterpret_cast<float4*>(&plds[r31][16 * ks + 8 * h + 4]) = p1;
    }
    const float* anb = annot + (size_t)(R0 + r31) * ADim + 8 * h;
#pragma unroll
    for (int ks = 0; ks < 2; ++ks) {
      float4 a0 = *reinterpret_cast<const float4*>(anb + 16 * ks);
      float4 a1 = *reinterpret_cast<const float4*>(anb + 16 * ks + 4);
      xan[ks] = cvt8(a0, a1);
    }
  }
  __syncthreads();

#define LDWP(base, ks, oh) \
  (*reinterpret_cast<const bf16x8*>(Wp + (((size_t)(base) + (ks) * 2 + (oh)) * 64 + l) * 8))

  f32x16 aR[2] = {zero16(), zero16()}, aZ[2] = {zero16(), zero16()};
#pragma unroll
  for (int ks = 0; ks < 8; ++ks) {
    bf16x8 af = (ks < 4) ? xa[ks] : xp[ks - 4];
#pragma unroll
    for (int oh = 0; oh < 2; ++oh) {
      aR[oh] = mm(af, LDWP(0, ks, oh), aR[oh]);
      aZ[oh] = mm(af, LDWP(16, ks, oh), aZ[oh]);
    }
  }
  const float br_[2] = {br[r31], br[32 + r31]};
  const float bz_[2] = {bz[r31], bz[32 + r31]};
  float propv[2][16], zv[2][16];
#pragma unroll
  for (int oh = 0; oh < 2; ++oh) {
#pragma unroll
    for (int reg = 0; reg < 16; ++reg) {
      int row = (reg & 3) + 8 * (reg >> 2) + 4 * h;
      int o = 32 * oh + r31;
      propv[oh][reg] = plds[row][o];
      float rv = sigm(aR[oh][reg] + br_[oh]);
      zv[oh][reg] = sigm(aZ[oh][reg] + bz_[oh]);
      tlds[row][o] = rv * propv[oh][reg];
    }
  }
  __syncthreads();
  bf16x8 xr[4];
#pragma unroll
  for (int ks = 0; ks < 4; ++ks) {
    float4 t0 = *reinterpret_cast<const float4*>(&tlds[r31][16 * ks + 8 * h]);
    float4 t1 = *reinterpret_cast<const float4*>(&tlds[r31][16 * ks + 8 * h + 4]);
    xr[ks] = cvt8(t0, t1);
  }
  f32x16 aH[2] = {zero16(), zero16()};
#pragma unroll
  for (int ks = 0; ks < 8; ++ks) {
    bf16x8 af = (ks < 4) ? xa[ks] : xr[ks - 4];
#pragma unroll
    for (int oh = 0; oh < 2; ++oh) aH[oh] = mm(af, LDWP(32, ks, oh), aH[oh]);
  }
  __syncthreads();
  const float bh_[2] = {bh[r31], bh[32 + r31]};
#pragma unroll
  for (int oh = 0; oh < 2; ++oh) {
#pragma unroll
    for (int reg = 0; reg < 16; ++reg) {
      int row = (reg & 3) + 8 * (reg >> 2) + 4 * h;
      int o = 32 * oh + r31;
      float hh = tanh_fast(aH[oh][reg] + bh_[oh]);
      float z = zv[oh][reg];
      tlds[row][o] = (1.f - z) * propv[oh][reg] + z * hh;
    }
  }
  __syncthreads();
  bf16x8 xn[4];
#pragma unroll
  for (int ks = 0; ks < 4; ++ks) {
    float4 t0 = *reinterpret_cast<const float4*>(&tlds[r31][16 * ks + 8 * h]);
    float4 t1 = *reinterpret_cast<const float4*>(&tlds[r31][16 * ks + 8 * h + 4]);
    xn[ks] = cvt8(t0, t1);
  }
  f32x16 aO[2] = {zero16(), zero16()};
#pragma unroll
  for (int ks = 0; ks < 6; ++ks) {
    bf16x8 af = (ks < 4) ? xn[ks] : xan[ks - 4];
#pragma unroll
    for (int oh = 0; oh < 2; ++oh) aO[oh] = mm(af, LDWP(48, ks, oh), aO[oh]);
  }
  const float bo1_[2] = {bo1[r31], bo1[32 + r31]};
  const float wo2_[2] = {Wo2[r31], Wo2[32 + r31]};
  const float bo2v = bo2[0];
#pragma unroll
  for (int reg = 0; reg < 16; ++reg) {
    float h0 = tanh_fast(aO[0][reg] + bo1_[0]);
    float h1 = tanh_fast(aO[1][reg] + bo1_[1]);
    float p = h0 * wo2_[0] + h1 * wo2_[1];
#pragma unroll
    for (int mks = 16; mks >= 1; mks >>= 1) p += __shfl_xor(p, mks, 64);
    if (r31 == 0) {
      int row = (reg & 3) + 8 * (reg >> 2) + 4 * h;
      out[R0 + row] = p + bo2v;
    }
  }
#undef LDWP
}

extern "C" void kernel_launch(void* const* d_in, const int* in_sizes, int n_in,
                              void* d_out, int out_size, void* d_ws, size_t ws_size,
                              hipStream_t stream) {
  const float* prop  = (const float*)d_in[0];
  const float* annot = (const float*)d_in[1];
  const float* A     = (const float*)d_in[2];
  const float* Win   = (const float*)d_in[3];
  const float* bin   = (const float*)d_in[4];
  const float* Wr    = (const float*)d_in[5];
  const float* br    = (const float*)d_in[6];
  const float* Wz    = (const float*)d_in[7];
  const float* bz    = (const float*)d_in[8];
  const float* Wh    = (const float*)d_in[9];
  const float* bh    = (const float*)d_in[10];
  const float* Wo1   = (const float*)d_in[11];
  const float* bo1   = (const float*)d_in[12];
  const float* Wo2   = (const float*)d_in[13];
  const float* bo2   = (const float*)d_in[14];
  float* out = (float*)d_out;

  char* ws = (char*)d_ws;
  __bf16* Bt   = (__bf16*)ws;                              // [2][64][16384] bf16 = 4 MB
  float*  part = (float*)(ws + (size_t)4 * 1024 * 1024);   // [8][256][32][64] f32 = 16 MB
  __bf16* Wp   = (__bf16*)(ws + (size_t)20 * 1024 * 1024); // 60 KB

  k_pack<<<dim3(60), 64, 0, stream>>>(Wr, Wz, Wh, Wo1, Wp);
  k_build_bt<<<dim3(Nn / 64, Ee, Bz), 256, 0, stream>>>(prop, Win, bin, Bt);
  k_big_gemm<<<dim3(256), 512, 0, stream>>>(A, Bt, part);
  k_gru<<<dim3(NT), 64, 0, stream>>>(part, prop, annot, Wp,
                                     br, bz, bh, bo1, Wo2, bo2, out);
}

// Round 11
// 133.964 us; speedup vs baseline: 1.2047x; 1.0057x over previous
//
#include <hip/hip_runtime.h>
#include <hip/hip_bf16.h>
#include <stdint.h>

typedef __bf16 bf16x8 __attribute__((ext_vector_type(8)));
typedef float  f32x16 __attribute__((ext_vector_type(16)));
typedef float  f32x4  __attribute__((ext_vector_type(4)));

static constexpr int Bz = 2, Nn = 4096, Ee = 4, Dd = 64, ADim = 32;
static constexpr int Mm = Nn * Ee;        // 16384 reduction dim
static constexpr int KSEG = 8;            // K-segments (== XCDs)
static constexpr int KLEN = Mm / KSEG;    // 2048 k per segment
static constexpr int NT = Bz * Nn / 32;   // 256 output row-tiles
static constexpr size_t SEGSTRIDE = (size_t)NT * 32 * 64;  // elems per kseg partial
static constexpr int PHK = 256;           // k per phase (1 KB/row A granule)
static constexpr int NPH = KLEN / PHK;    // 8 phases

__device__ __forceinline__ bf16x8 cvt8(float4 a, float4 b) {
  bf16x8 r;
  r[0] = (__bf16)a.x; r[1] = (__bf16)a.y; r[2] = (__bf16)a.z; r[3] = (__bf16)a.w;
  r[4] = (__bf16)b.x; r[5] = (__bf16)b.y; r[6] = (__bf16)b.z; r[7] = (__bf16)b.w;
  return r;
}
__device__ __forceinline__ bf16x8 cvt8v(f32x4 a, f32x4 b) {
  bf16x8 r;
  r[0] = (__bf16)a[0]; r[1] = (__bf16)a[1]; r[2] = (__bf16)a[2]; r[3] = (__bf16)a[3];
  r[4] = (__bf16)b[0]; r[5] = (__bf16)b[1]; r[6] = (__bf16)b[2]; r[7] = (__bf16)b[3];
  return r;
}
__device__ __forceinline__ f32x16 zero16() {
  f32x16 z;
#pragma unroll
  for (int i = 0; i < 16; ++i) z[i] = 0.f;
  return z;
}
__device__ __forceinline__ f32x16 mm(bf16x8 a, bf16x8 b, f32x16 c) {
  return __builtin_amdgcn_mfma_f32_32x32x16_bf16(a, b, c, 0, 0, 0);
}
__device__ __forceinline__ float sigm(float x) { return 1.f / (1.f + __expf(-x)); }
__device__ __forceinline__ float tanh_fast(float x) {
  float e = __expf(2.f * x);
  return 1.f - 2.f / (e + 1.f);
}
__device__ __forceinline__ void async_lds16(const void* g, void* l) {
  __builtin_amdgcn_global_load_lds(
      (const __attribute__((address_space(1))) uint32_t*)g,
      (__attribute__((address_space(3))) uint32_t*)l, 16, 0, 0);
}

// -------- Kernel 1: fused weight-pack (block 512) + Bt build (blocks 0..511).
// Bt[b][d][e*N+n] = sum_d' W_in[e][d][d'] * prop[b][n][d'] + b_in[e][d]
__global__ __launch_bounds__(256) void k_packbt(
    const float* __restrict__ prop, const float* __restrict__ Win,
    const float* __restrict__ bin, __bf16* __restrict__ Bt,
    const float* __restrict__ Wr, const float* __restrict__ Wz,
    const float* __restrict__ Wh, const float* __restrict__ Wo1,
    __bf16* __restrict__ Wp) {
  const int bid = blockIdx.x;
  const int tid = threadIdx.x;
  const int w = tid >> 6, l = tid & 63;
  const int r31 = l & 31, h = l >> 5;

  if (bid == 512) {
    // ---- pack role: 60 weight fragments, 4 waves stride-4
    for (int f = w; f < 60; f += 4) {
      const float* W; int L, fl;
      if (f < 16)      { W = Wr;  L = 128; fl = f; }
      else if (f < 32) { W = Wz;  L = 128; fl = f - 16; }
      else if (f < 48) { W = Wh;  L = 128; fl = f - 32; }
      else             { W = Wo1; L = 96;  fl = f - 48; }
      const int ks = fl >> 1, oh = fl & 1;
      const float* src = W + (size_t)(32 * oh + r31) * L + 16 * ks + 8 * h;
      float4 s0 = *reinterpret_cast<const float4*>(src);
      float4 s1 = *reinterpret_cast<const float4*>(src + 4);
      *reinterpret_cast<bf16x8*>(Wp + ((size_t)f * 64 + l) * 8) = cvt8(s0, s1);
    }
    return;
  }
  // ---- Bt role
  const int nchunk = bid & 63;
  const int e = (bid >> 6) & 3, b = bid >> 8;
  const int oh = w & 1, ns = w >> 1;
  const int o_row = oh * 32 + r31;
  const int n_col = nchunk * 64 + ns * 32 + r31;
  const float* wbase = Win + ((size_t)e * 64 + o_row) * 64 + 8 * h;
  const float* pbase = prop + ((size_t)b * Nn + n_col) * 64 + 8 * h;
  f32x16 acc = zero16();
#pragma unroll
  for (int ks = 0; ks < 4; ++ks) {
    float4 w0 = *reinterpret_cast<const float4*>(wbase + 16 * ks);
    float4 w1 = *reinterpret_cast<const float4*>(wbase + 16 * ks + 4);
    float4 p0 = *reinterpret_cast<const float4*>(pbase + 16 * ks);
    float4 p1 = *reinterpret_cast<const float4*>(pbase + 16 * ks + 4);
    acc = mm(cvt8(w0, w1), cvt8(p0, p1), acc);
  }
#pragma unroll
  for (int reg = 0; reg < 16; ++reg) {
    int orow = oh * 32 + (reg & 3) + 8 * (reg >> 2) + 4 * h;
    float v = acc[reg] + bin[e * 64 + orow];
    Bt[((size_t)b * 64 + orow) * Mm + (size_t)e * Nn + n_col] = (__bf16)v;
  }
}

// -------- Kernel 2: split-K GEMM (R10 structure, unchanged except bf16 part).
// 256 blocks (1/CU). kseg = bid&7. 8 tiles/block as 4 pairs; A ping-pong
// halves; Bt register-dbuf; raw s_barrier + counted vmcnt (never 0 in loop).
__global__ __launch_bounds__(512, 1) void k_big_gemm(
    const float* __restrict__ A, const __bf16* __restrict__ Bt,
    __bf16* __restrict__ part) {
  __shared__ float  ahalf[2][64][PHK];   // 2 x 64 KB
  __shared__ __bf16 btl[64][PHK];        // 32 KB  (total 160 KiB)

  const int bid = blockIdx.x;            // 0..255
  const int kseg = bid & 7;
  const int tg   = bid >> 3;             // 0..31
  const int bb   = tg >> 4;
  const int gg   = tg & 15;              // 8-tile group within batch
  const int ph0  = tg & (NPH - 1);       // phase rotation
  const int tid = threadIdx.x;
  const int w = tid >> 6, l = tid & 63;
  const int r31 = l & 31, h = l >> 5;
  const int tp = w >> 2, q = (w >> 1) & 1, kh = w & 1;

  const size_t kbase = (size_t)kseg * KLEN;
  const float*  Ab  = A  + ((size_t)bb * Nn + gg * 256) * Mm + kbase;
  const __bf16* BtB = Bt + (size_t)bb * 64 * Mm + kbase;

#define ISSUE_A(pi, pr, hf)                                                  \
  { _Pragma("unroll")                                                        \
    for (int j_ = 0; j_ < 8; ++j_) {                                         \
      const int rw_ = 8 * w + j_;                                            \
      const float* src_ = Ab + (size_t)((pi) * 64 + rw_) * Mm +              \
                          (size_t)(pr) * PHK + ((l ^ (rw_ & 7)) << 2);       \
      async_lds16(src_, (void*)&ahalf[hf][rw_][0]);                          \
    } }

  bf16x8 btreg[4];
  const int btrh = l >> 5;
  const int btu  = l & 31;
#define LOAD_BT(pr)                                                          \
  { _Pragma("unroll")                                                        \
    for (int j_ = 0; j_ < 4; ++j_) {                                         \
      const int row_ = 8 * w + 2 * j_ + btrh;                                \
      btreg[j_] = *reinterpret_cast<const bf16x8*>(                          \
          BtB + (size_t)row_ * Mm + (size_t)(pr) * PHK + btu * 8);           \
    } }
#define WRITE_BT                                                             \
  { _Pragma("unroll")                                                        \
    for (int j_ = 0; j_ < 4; ++j_) {                                         \
      const int row_ = 8 * w + 2 * j_ + btrh;                                \
      *reinterpret_cast<bf16x8*>(&btl[row_][(btu ^ (row_ & 7)) * 8]) =       \
          btreg[j_];                                                         \
    } }

  const int swz  = r31 & 7;
  const int arow = tp * 32 + r31;
  const int brow = 32 * q + r31;
  f32x16 acc[4] = {zero16(), zero16(), zero16(), zero16()};

#define COMPUTE(pi, hf)                                                      \
  { _Pragma("unroll")                                                        \
    for (int s_ = 0; s_ < 8; ++s_) {                                         \
      const int ua_ = kh * 32 + 4 * s_ + 2 * h;                              \
      f32x4 fa0 = *reinterpret_cast<const f32x4*>(                           \
          &ahalf[hf][arow][((ua_ ^ swz) << 2)]);                             \
      f32x4 fa1 = *reinterpret_cast<const f32x4*>(                           \
          &ahalf[hf][arow][(((ua_ + 1) ^ swz) << 2)]);                       \
      const int ub_ = kh * 16 + 2 * s_ + h;                                  \
      bf16x8 fb = *reinterpret_cast<const bf16x8*>(                          \
          &btl[brow][((ub_ ^ swz) * 8)]);                                    \
      acc[pi] = mm(cvt8v(fa0, fa1), fb, acc[pi]);                            \
    } }

  LOAD_BT(ph0);
  ISSUE_A(0, ph0, 0);
  ISSUE_A(1, ph0, 1);
  asm volatile("s_waitcnt vmcnt(16)" ::: "memory");
  WRITE_BT;
  asm volatile("s_waitcnt vmcnt(8) lgkmcnt(0)" ::: "memory");
  __builtin_amdgcn_s_barrier();

  for (int pp = 0; pp < NPH; ++pp) {
    const bool lastp = (pp == NPH - 1);
    const int prc = (pp + ph0) & (NPH - 1);
    const int prn = (pp + 1 + ph0) & (NPH - 1);
    COMPUTE(0, 0);
    __builtin_amdgcn_s_barrier();
    ISSUE_A(2, prc, 0);
    asm volatile("s_waitcnt vmcnt(8)" ::: "memory");
    __builtin_amdgcn_s_barrier();
    COMPUTE(1, 1);
    __builtin_amdgcn_s_barrier();
    if (!lastp) LOAD_BT(prn);
    ISSUE_A(3, prc, 1);
    asm volatile("s_waitcnt vmcnt(8)" ::: "memory");
    __builtin_amdgcn_s_barrier();
    COMPUTE(2, 0);
    __builtin_amdgcn_s_barrier();
    if (!lastp) {
      ISSUE_A(0, prn, 0);
      asm volatile("s_waitcnt vmcnt(8)" ::: "memory");
    } else {
      asm volatile("s_waitcnt vmcnt(0)" ::: "memory");
    }
    __builtin_amdgcn_s_barrier();
    COMPUTE(3, 1);
    if (!lastp) {
      __builtin_amdgcn_s_barrier();
      WRITE_BT;
      ISSUE_A(1, prn, 1);
      asm volatile("s_waitcnt vmcnt(8) lgkmcnt(0)" ::: "memory");
      __builtin_amdgcn_s_barrier();
    }
  }
#undef ISSUE_A
#undef LOAD_BT
#undef WRITE_BT
#undef COMPUTE

  // epilogue: kh-pair reduce via half0 scratch, store bf16 partials
  float* scratch = &ahalf[0][0][0];
  if (kh == 1) {
#pragma unroll
    for (int i = 0; i < 4; ++i) {
      float* slot = scratch + (size_t)(i * 4 + tp * 2 + q) * 1024 + l * 16;
#pragma unroll
      for (int r = 0; r < 16; r += 4) {
        f32x4 v; v[0] = acc[i][r]; v[1] = acc[i][r + 1];
        v[2] = acc[i][r + 2]; v[3] = acc[i][r + 3];
        *reinterpret_cast<f32x4*>(slot + r) = v;
      }
    }
  }
  __syncthreads();
  if (kh == 0) {
#pragma unroll
    for (int i = 0; i < 4; ++i) {
      const int tile = bb * 128 + gg * 8 + i * 2 + tp;
      __bf16* pb = part + (size_t)kseg * SEGSTRIDE + (size_t)tile * 32 * 64 + 32 * q;
      const float* slot = scratch + (size_t)(i * 4 + tp * 2 + q) * 1024 + l * 16;
#pragma unroll
      for (int reg = 0; reg < 16; ++reg) {
        int row = (reg & 3) + 8 * (reg >> 2) + 4 * h;
        pb[row * 64 + r31] = (__bf16)(acc[i][reg] + slot[reg]);
      }
    }
  }
}

// -------- Kernel 3: fold split-K reduce (8 bf16 segs) + GRU update + head.
__global__ __launch_bounds__(64) void k_gru(
    const __bf16* __restrict__ part, const float* __restrict__ prop,
    const float* __restrict__ annot, const __bf16* __restrict__ Wp,
    const float* __restrict__ br, const float* __restrict__ bz,
    const float* __restrict__ bh, const float* __restrict__ bo1,
    const float* __restrict__ Wo2, const float* __restrict__ bo2,
    float* __restrict__ out) {
  __shared__ float plds[32][68];
  __shared__ float tlds[32][68];
  const int tile = blockIdx.x;
  const int R0 = tile * 32;
  const int l = threadIdx.x;
  const int r31 = l & 31, h = l >> 5;

  bf16x8 xa[4], xp[4], xan[2];
  {
    const __bf16* pt = part + ((size_t)tile * 32 + r31) * 64 + 8 * h;
    const float* pb = prop + (size_t)(R0 + r31) * 64 + 8 * h;
#pragma unroll
    for (int ks = 0; ks < 4; ++ks) {
      float s[8] = {0.f, 0.f, 0.f, 0.f, 0.f, 0.f, 0.f, 0.f};
#pragma unroll
      for (int seg = 0; seg < KSEG; ++seg) {
        bf16x8 v = *reinterpret_cast<const bf16x8*>(pt + seg * SEGSTRIDE + 16 * ks);
#pragma unroll
        for (int j = 0; j < 8; ++j) s[j] += (float)v[j];
      }
      bf16x8 x;
#pragma unroll
      for (int j = 0; j < 8; ++j) x[j] = (__bf16)s[j];
      xa[ks] = x;
      float4 p0 = *reinterpret_cast<const float4*>(pb + 16 * ks);
      float4 p1 = *reinterpret_cast<const float4*>(pb + 16 * ks + 4);
      xp[ks] = cvt8(p0, p1);
      *reinterpret_cast<float4*>(&plds[r31][16 * ks + 8 * h]) = p0;
      *reinterpret_cast<float4*>(&plds[r31][16 * ks + 8 * h + 4]) = p1;
    }
    const float* anb = annot + (size_t)(R0 + r31) * ADim + 8 * h;
#pragma unroll
    for (int ks = 0; ks < 2; ++ks) {
      float4 a0 = *reinterpret_cast<const float4*>(anb + 16 * ks);
      float4 a1 = *reinterpret_cast<const float4*>(anb + 16 * ks + 4);
      xan[ks] = cvt8(a0, a1);
    }
  }
  __syncthreads();

#define LDWP(base, ks, oh) \
  (*reinterpret_cast<const bf16x8*>(Wp + (((size_t)(base) + (ks) * 2 + (oh)) * 64 + l) * 8))

  f32x16 aR[2] = {zero16(), zero16()}, aZ[2] = {zero16(), zero16()};
#pragma unroll
  for (int ks = 0; ks < 8; ++ks) {
    bf16x8 af = (ks < 4) ? xa[ks] : xp[ks - 4];
#pragma unroll
    for (int oh = 0; oh < 2; ++oh) {
      aR[oh] = mm(af, LDWP(0, ks, oh), aR[oh]);
      aZ[oh] = mm(af, LDWP(16, ks, oh), aZ[oh]);
    }
  }
  const float br_[2] = {br[r31], br[32 + r31]};
  const float bz_[2] = {bz[r31], bz[32 + r31]};
  float propv[2][16], zv[2][16];
#pragma unroll
  for (int oh = 0; oh < 2; ++oh) {
#pragma unroll
    for (int reg = 0; reg < 16; ++reg) {
      int row = (reg & 3) + 8 * (reg >> 2) + 4 * h;
      int o = 32 * oh + r31;
      propv[oh][reg] = plds[row][o];
      float rv = sigm(aR[oh][reg] + br_[oh]);
      zv[oh][reg] = sigm(aZ[oh][reg] + bz_[oh]);
      tlds[row][o] = rv * propv[oh][reg];
    }
  }
  __syncthreads();
  bf16x8 xr[4];
#pragma unroll
  for (int ks = 0; ks < 4; ++ks) {
    float4 t0 = *reinterpret_cast<const float4*>(&tlds[r31][16 * ks + 8 * h]);
    float4 t1 = *reinterpret_cast<const float4*>(&tlds[r31][16 * ks + 8 * h + 4]);
    xr[ks] = cvt8(t0, t1);
  }
  f32x16 aH[2] = {zero16(), zero16()};
#pragma unroll
  for (int ks = 0; ks < 8; ++ks) {
    bf16x8 af = (ks < 4) ? xa[ks] : xr[ks - 4];
#pragma unroll
    for (int oh = 0; oh < 2; ++oh) aH[oh] = mm(af, LDWP(32, ks, oh), aH[oh]);
  }
  __syncthreads();
  const float bh_[2] = {bh[r31], bh[32 + r31]};
#pragma unroll
  for (int oh = 0; oh < 2; ++oh) {
#pragma unroll
    for (int reg = 0; reg < 16; ++reg) {
      int row = (reg & 3) + 8 * (reg >> 2) + 4 * h;
      int o = 32 * oh + r31;
      float hh = tanh_fast(aH[oh][reg] + bh_[oh]);
      float z = zv[oh][reg];
      tlds[row][o] = (1.f - z) * propv[oh][reg] + z * hh;
    }
  }
  __syncthreads();
  bf16x8 xn[4];
#pragma unroll
  for (int ks = 0; ks < 4; ++ks) {
    float4 t0 = *reinterpret_cast<const float4*>(&tlds[r31][16 * ks + 8 * h]);
    float4 t1 = *reinterpret_cast<const float4*>(&tlds[r31][16 * ks + 8 * h + 4]);
    xn[ks] = cvt8(t0, t1);
  }
  f32x16 aO[2] = {zero16(), zero16()};
#pragma unroll
  for (int ks = 0; ks < 6; ++ks) {
    bf16x8 af = (ks < 4) ? xn[ks] : xan[ks - 4];
#pragma unroll
    for (int oh = 0; oh < 2; ++oh) aO[oh] = mm(af, LDWP(48, ks, oh), aO[oh]);
  }
  const float bo1_[2] = {bo1[r31], bo1[32 + r31]};
  const float wo2_[2] = {Wo2[r31], Wo2[32 + r31]};
  const float bo2v = bo2[0];
#pragma unroll
  for (int reg = 0; reg < 16; ++reg) {
    float h0 = tanh_fast(aO[0][reg] + bo1_[0]);
    float h1 = tanh_fast(aO[1][reg] + bo1_[1]);
    float p = h0 * wo2_[0] + h1 * wo2_[1];
#pragma unroll
    for (int mks = 16; mks >= 1; mks >>= 1) p += __shfl_xor(p, mks, 64);
    if (r31 == 0) {
      int row = (reg & 3) + 8 * (reg >> 2) + 4 * h;
      out[R0 + row] = p + bo2v;
    }
  }
#undef LDWP
}

extern "C" void kernel_launch(void* const* d_in, const int* in_sizes, int n_in,
                              void* d_out, int out_size, void* d_ws, size_t ws_size,
                              hipStream_t stream) {
  const float* prop  = (const float*)d_in[0];
  const float* annot = (const float*)d_in[1];
  const float* A     = (const float*)d_in[2];
  const float* Win   = (const float*)d_in[3];
  const float* bin   = (const float*)d_in[4];
  const float* Wr    = (const float*)d_in[5];
  const float* br    = (const float*)d_in[6];
  const float* Wz    = (const float*)d_in[7];
  const float* bz    = (const float*)d_in[8];
  const float* Wh    = (const float*)d_in[9];
  const float* bh    = (const float*)d_in[10];
  const float* Wo1   = (const float*)d_in[11];
  const float* bo1   = (const float*)d_in[12];
  const float* Wo2   = (const float*)d_in[13];
  const float* bo2   = (const float*)d_in[14];
  float* out = (float*)d_out;

  char* ws = (char*)d_ws;
  __bf16* Bt   = (__bf16*)ws;                              // [2][64][16384] bf16 = 4 MB
  __bf16* part = (__bf16*)(ws + (size_t)4 * 1024 * 1024);  // [8][256][32][64] bf16 = 8 MB
  __bf16* Wp   = (__bf16*)(ws + (size_t)16 * 1024 * 1024); // 60 KB

  k_packbt<<<dim3(513), 256, 0, stream>>>(prop, Win, bin, Bt,
                                          Wr, Wz, Wh, Wo1, Wp);
  k_big_gemm<<<dim3(256), 512, 0, stream>>>(A, Bt, part);
  k_gru<<<dim3(NT), 64, 0, stream>>>(part, prop, annot, Wp,
                                     br, bz, bh, bo1, Wo2, bo2, out);
}

// Round 12
// 127.466 us; speedup vs baseline: 1.2661x; 1.0510x over previous
//
#include <hip/hip_runtime.h>
#include <hip/hip_bf16.h>
#include <stdint.h>

typedef __bf16 bf16x8 __attribute__((ext_vector_type(8)));
typedef float  f32x16 __attribute__((ext_vector_type(16)));
typedef float  f32x4  __attribute__((ext_vector_type(4)));

static constexpr int Bz = 2, Nn = 4096, Ee = 4, Dd = 64, ADim = 32;
static constexpr int Mm = Nn * Ee;        // 16384 reduction dim
static constexpr int KSEG = 8;            // K-segments (== XCDs)
static constexpr int KLEN = Mm / KSEG;    // 2048 k per segment
static constexpr int NT = Bz * Nn / 32;   // 256 output row-tiles
static constexpr int PHK = 256;           // k per phase (1 KB/row A granule)
static constexpr int NPH = KLEN / PHK;    // 8 phases

__device__ __forceinline__ bf16x8 cvt8(float4 a, float4 b) {
  bf16x8 r;
  r[0] = (__bf16)a.x; r[1] = (__bf16)a.y; r[2] = (__bf16)a.z; r[3] = (__bf16)a.w;
  r[4] = (__bf16)b.x; r[5] = (__bf16)b.y; r[6] = (__bf16)b.z; r[7] = (__bf16)b.w;
  return r;
}
__device__ __forceinline__ bf16x8 cvt8v(f32x4 a, f32x4 b) {
  bf16x8 r;
  r[0] = (__bf16)a[0]; r[1] = (__bf16)a[1]; r[2] = (__bf16)a[2]; r[3] = (__bf16)a[3];
  r[4] = (__bf16)b[0]; r[5] = (__bf16)b[1]; r[6] = (__bf16)b[2]; r[7] = (__bf16)b[3];
  return r;
}
__device__ __forceinline__ f32x16 zero16() {
  f32x16 z;
#pragma unroll
  for (int i = 0; i < 16; ++i) z[i] = 0.f;
  return z;
}
__device__ __forceinline__ f32x16 mm(bf16x8 a, bf16x8 b, f32x16 c) {
  return __builtin_amdgcn_mfma_f32_32x32x16_bf16(a, b, c, 0, 0, 0);
}
__device__ __forceinline__ float sigm(float x) { return 1.f / (1.f + __expf(-x)); }
__device__ __forceinline__ float tanh_fast(float x) {
  float e = __expf(2.f * x);
  return 1.f - 2.f / (e + 1.f);
}
__device__ __forceinline__ void async_lds16(const void* g, void* l) {
  __builtin_amdgcn_global_load_lds(
      (const __attribute__((address_space(1))) uint32_t*)g,
      (__attribute__((address_space(3))) uint32_t*)l, 16, 0, 0);
}

// -------- Kernel 1: fused weight-pack (block 512) + Bt build (blocks 0..511).
__global__ __launch_bounds__(256) void k_packbt(
    const float* __restrict__ prop, const float* __restrict__ Win,
    const float* __restrict__ bin, __bf16* __restrict__ Bt,
    const float* __restrict__ Wr, const float* __restrict__ Wz,
    const float* __restrict__ Wh, const float* __restrict__ Wo1,
    __bf16* __restrict__ Wp) {
  const int bid = blockIdx.x;
  const int tid = threadIdx.x;
  const int w = tid >> 6, l = tid & 63;
  const int r31 = l & 31, h = l >> 5;

  if (bid == 512) {
    for (int f = w; f < 60; f += 4) {
      const float* W; int L, fl;
      if (f < 16)      { W = Wr;  L = 128; fl = f; }
      else if (f < 32) { W = Wz;  L = 128; fl = f - 16; }
      else if (f < 48) { W = Wh;  L = 128; fl = f - 32; }
      else             { W = Wo1; L = 96;  fl = f - 48; }
      const int ks = fl >> 1, oh = fl & 1;
      const float* src = W + (size_t)(32 * oh + r31) * L + 16 * ks + 8 * h;
      float4 s0 = *reinterpret_cast<const float4*>(src);
      float4 s1 = *reinterpret_cast<const float4*>(src + 4);
      *reinterpret_cast<bf16x8*>(Wp + ((size_t)f * 64 + l) * 8) = cvt8(s0, s1);
    }
    return;
  }
  const int nchunk = bid & 63;
  const int e = (bid >> 6) & 3, b = bid >> 8;
  const int oh = w & 1, ns = w >> 1;
  const int o_row = oh * 32 + r31;
  const int n_col = nchunk * 64 + ns * 32 + r31;
  const float* wbase = Win + ((size_t)e * 64 + o_row) * 64 + 8 * h;
  const float* pbase = prop + ((size_t)b * Nn + n_col) * 64 + 8 * h;
  f32x16 acc = zero16();
#pragma unroll
  for (int ks = 0; ks < 4; ++ks) {
    float4 w0 = *reinterpret_cast<const float4*>(wbase + 16 * ks);
    float4 w1 = *reinterpret_cast<const float4*>(wbase + 16 * ks + 4);
    float4 p0 = *reinterpret_cast<const float4*>(pbase + 16 * ks);
    float4 p1 = *reinterpret_cast<const float4*>(pbase + 16 * ks + 4);
    acc = mm(cvt8(w0, w1), cvt8(p0, p1), acc);
  }
#pragma unroll
  for (int reg = 0; reg < 16; ++reg) {
    int orow = oh * 32 + (reg & 3) + 8 * (reg >> 2) + 4 * h;
    float v = acc[reg] + bin[e * 64 + orow];
    Bt[((size_t)b * 64 + orow) * Mm + (size_t)e * Nn + n_col] = (__bf16)v;
  }
}

// -------- Kernel 2: split-K GEMM (R10/R11 structure; part layout [tile][seg]).
__global__ __launch_bounds__(512, 1) void k_big_gemm(
    const float* __restrict__ A, const __bf16* __restrict__ Bt,
    __bf16* __restrict__ part) {
  __shared__ float  ahalf[2][64][PHK];   // 2 x 64 KB
  __shared__ __bf16 btl[64][PHK];        // 32 KB  (total 160 KiB)

  const int bid = blockIdx.x;            // 0..255
  const int kseg = bid & 7;
  const int tg   = bid >> 3;             // 0..31
  const int bb   = tg >> 4;
  const int gg   = tg & 15;              // 8-tile group within batch
  const int ph0  = tg & (NPH - 1);       // phase rotation
  const int tid = threadIdx.x;
  const int w = tid >> 6, l = tid & 63;
  const int r31 = l & 31, h = l >> 5;
  const int tp = w >> 2, q = (w >> 1) & 1, kh = w & 1;

  const size_t kbase = (size_t)kseg * KLEN;
  const float*  Ab  = A  + ((size_t)bb * Nn + gg * 256) * Mm + kbase;
  const __bf16* BtB = Bt + (size_t)bb * 64 * Mm + kbase;

#define ISSUE_A(pi, pr, hf)                                                  \
  { _Pragma("unroll")                                                        \
    for (int j_ = 0; j_ < 8; ++j_) {                                         \
      const int rw_ = 8 * w + j_;                                            \
      const float* src_ = Ab + (size_t)((pi) * 64 + rw_) * Mm +              \
                          (size_t)(pr) * PHK + ((l ^ (rw_ & 7)) << 2);       \
      async_lds16(src_, (void*)&ahalf[hf][rw_][0]);                          \
    } }

  bf16x8 btreg[4];
  const int btrh = l >> 5;
  const int btu  = l & 31;
#define LOAD_BT(pr)                                                          \
  { _Pragma("unroll")                                                        \
    for (int j_ = 0; j_ < 4; ++j_) {                                         \
      const int row_ = 8 * w + 2 * j_ + btrh;                                \
      btreg[j_] = *reinterpret_cast<const bf16x8*>(                          \
          BtB + (size_t)row_ * Mm + (size_t)(pr) * PHK + btu * 8);           \
    } }
#define WRITE_BT                                                             \
  { _Pragma("unroll")                                                        \
    for (int j_ = 0; j_ < 4; ++j_) {                                         \
      const int row_ = 8 * w + 2 * j_ + btrh;                                \
      *reinterpret_cast<bf16x8*>(&btl[row_][(btu ^ (row_ & 7)) * 8]) =       \
          btreg[j_];                                                         \
    } }

  const int swz  = r31 & 7;
  const int arow = tp * 32 + r31;
  const int brow = 32 * q + r31;
  f32x16 acc[4] = {zero16(), zero16(), zero16(), zero16()};

#define COMPUTE(pi, hf)                                                      \
  { _Pragma("unroll")                                                        \
    for (int s_ = 0; s_ < 8; ++s_) {                                         \
      const int ua_ = kh * 32 + 4 * s_ + 2 * h;                              \
      f32x4 fa0 = *reinterpret_cast<const f32x4*>(                           \
          &ahalf[hf][arow][((ua_ ^ swz) << 2)]);                             \
      f32x4 fa1 = *reinterpret_cast<const f32x4*>(                           \
          &ahalf[hf][arow][(((ua_ + 1) ^ swz) << 2)]);                       \
      const int ub_ = kh * 16 + 2 * s_ + h;                                  \
      bf16x8 fb = *reinterpret_cast<const bf16x8*>(                          \
          &btl[brow][((ub_ ^ swz) * 8)]);                                    \
      acc[pi] = mm(cvt8v(fa0, fa1), fb, acc[pi]);                            \
    } }

  LOAD_BT(ph0);
  ISSUE_A(0, ph0, 0);
  ISSUE_A(1, ph0, 1);
  asm volatile("s_waitcnt vmcnt(16)" ::: "memory");
  WRITE_BT;
  asm volatile("s_waitcnt vmcnt(8) lgkmcnt(0)" ::: "memory");
  __builtin_amdgcn_s_barrier();

  for (int pp = 0; pp < NPH; ++pp) {
    const bool lastp = (pp == NPH - 1);
    const int prc = (pp + ph0) & (NPH - 1);
    const int prn = (pp + 1 + ph0) & (NPH - 1);
    COMPUTE(0, 0);
    __builtin_amdgcn_s_barrier();
    ISSUE_A(2, prc, 0);
    asm volatile("s_waitcnt vmcnt(8)" ::: "memory");
    __builtin_amdgcn_s_barrier();
    COMPUTE(1, 1);
    __builtin_amdgcn_s_barrier();
    if (!lastp) LOAD_BT(prn);
    ISSUE_A(3, prc, 1);
    asm volatile("s_waitcnt vmcnt(8)" ::: "memory");
    __builtin_amdgcn_s_barrier();
    COMPUTE(2, 0);
    __builtin_amdgcn_s_barrier();
    if (!lastp) {
      ISSUE_A(0, prn, 0);
      asm volatile("s_waitcnt vmcnt(8)" ::: "memory");
    } else {
      asm volatile("s_waitcnt vmcnt(0)" ::: "memory");
    }
    __builtin_amdgcn_s_barrier();
    COMPUTE(3, 1);
    if (!lastp) {
      __builtin_amdgcn_s_barrier();
      WRITE_BT;
      ISSUE_A(1, prn, 1);
      asm volatile("s_waitcnt vmcnt(8) lgkmcnt(0)" ::: "memory");
      __builtin_amdgcn_s_barrier();
    }
  }
#undef ISSUE_A
#undef LOAD_BT
#undef WRITE_BT
#undef COMPUTE

  // epilogue: kh-pair reduce via half0 scratch, store bf16 partials.
  // part layout: [tile][kseg][32][64] bf16 (tile-major for k_gru locality)
  float* scratch = &ahalf[0][0][0];
  if (kh == 1) {
#pragma unroll
    for (int i = 0; i < 4; ++i) {
      float* slot = scratch + (size_t)(i * 4 + tp * 2 + q) * 1024 + l * 16;
#pragma unroll
      for (int r = 0; r < 16; r += 4) {
        f32x4 v; v[0] = acc[i][r]; v[1] = acc[i][r + 1];
        v[2] = acc[i][r + 2]; v[3] = acc[i][r + 3];
        *reinterpret_cast<f32x4*>(slot + r) = v;
      }
    }
  }
  __syncthreads();
  if (kh == 0) {
#pragma unroll
    for (int i = 0; i < 4; ++i) {
      const int tile = bb * 128 + gg * 8 + i * 2 + tp;
      __bf16* pb = part + ((size_t)tile * KSEG + kseg) * 2048 + 32 * q;
      const float* slot = scratch + (size_t)(i * 4 + tp * 2 + q) * 1024 + l * 16;
#pragma unroll
      for (int reg = 0; reg < 16; ++reg) {
        int row = (reg & 3) + 8 * (reg >> 2) + 4 * h;
        pb[row * 64 + r31] = (__bf16)(acc[i][reg] + slot[reg]);
      }
    }
  }
}

// -------- Kernel 3: 2-wave GRU (oh split across waves) + split-K fold + head.
__global__ __launch_bounds__(128) void k_gru(
    const __bf16* __restrict__ part, const float* __restrict__ prop,
    const float* __restrict__ annot, const __bf16* __restrict__ Wp,
    const float* __restrict__ br, const float* __restrict__ bz,
    const float* __restrict__ bh, const float* __restrict__ bo1,
    const float* __restrict__ Wo2, const float* __restrict__ bo2,
    float* __restrict__ out) {
  __shared__ float plds[32][68];
  __shared__ float tlds[32][68];
  __shared__ float sred[32];
  const int tile = blockIdx.x;
  const int R0 = tile * 32;
  const int tid = threadIdx.x;
  const int wv = tid >> 6;          // wave = oh half (0/1)
  const int l = tid & 63;
  const int r31 = l & 31, h = l >> 5;

  bf16x8 xa[4], xp[4], xan[2];
  {
    // a_in tile = sum over 8 k-segment bf16 partials (tile-major layout)
    const __bf16* pt = part + (size_t)tile * (KSEG * 2048) + (size_t)r31 * 64 + 8 * h;
    const float* pb = prop + (size_t)(R0 + r31) * 64 + 8 * h;
#pragma unroll
    for (int ks = 0; ks < 4; ++ks) {
      float s[8] = {0.f, 0.f, 0.f, 0.f, 0.f, 0.f, 0.f, 0.f};
#pragma unroll
      for (int seg = 0; seg < KSEG; ++seg) {
        bf16x8 v = *reinterpret_cast<const bf16x8*>(pt + seg * 2048 + 16 * ks);
#pragma unroll
        for (int j = 0; j < 8; ++j) s[j] += (float)v[j];
      }
      bf16x8 x;
#pragma unroll
      for (int j = 0; j < 8; ++j) x[j] = (__bf16)s[j];
      xa[ks] = x;
      float4 p0 = *reinterpret_cast<const float4*>(pb + 16 * ks);
      float4 p1 = *reinterpret_cast<const float4*>(pb + 16 * ks + 4);
      xp[ks] = cvt8(p0, p1);
      if (wv == 0) {
        *reinterpret_cast<float4*>(&plds[r31][16 * ks + 8 * h]) = p0;
        *reinterpret_cast<float4*>(&plds[r31][16 * ks + 8 * h + 4]) = p1;
      }
    }
    const float* anb = annot + (size_t)(R0 + r31) * ADim + 8 * h;
#pragma unroll
    for (int ks = 0; ks < 2; ++ks) {
      float4 a0 = *reinterpret_cast<const float4*>(anb + 16 * ks);
      float4 a1 = *reinterpret_cast<const float4*>(anb + 16 * ks + 4);
      xan[ks] = cvt8(a0, a1);
    }
  }
  __syncthreads();

#define LDWP(base, ks, oh) \
  (*reinterpret_cast<const bf16x8*>(Wp + (((size_t)(base) + (ks) * 2 + (oh)) * 64 + l) * 8))

  // ---- stage 1: gates r,z — wave wv computes oh = wv half only
  f32x16 aR = zero16(), aZ = zero16();
#pragma unroll
  for (int ks = 0; ks < 8; ++ks) {
    bf16x8 af = (ks < 4) ? xa[ks] : xp[ks - 4];
    aR = mm(af, LDWP(0, ks, wv), aR);
    aZ = mm(af, LDWP(16, ks, wv), aZ);
  }
  const float br_ = br[32 * wv + r31];
  const float bz_ = bz[32 * wv + r31];
  float propv[16], zv[16];
  const int oc = 32 * wv + r31;
#pragma unroll
  for (int reg = 0; reg < 16; ++reg) {
    int row = (reg & 3) + 8 * (reg >> 2) + 4 * h;
    propv[reg] = plds[row][oc];
    float rv = sigm(aR[reg] + br_);
    zv[reg] = sigm(aZ[reg] + bz_);
    tlds[row][oc] = rv * propv[reg];
  }
  __syncthreads();
  bf16x8 xr[4];
#pragma unroll
  for (int ks = 0; ks < 4; ++ks) {
    float4 t0 = *reinterpret_cast<const float4*>(&tlds[r31][16 * ks + 8 * h]);
    float4 t1 = *reinterpret_cast<const float4*>(&tlds[r31][16 * ks + 8 * h + 4]);
    xr[ks] = cvt8(t0, t1);
  }
  // ---- stage 2: candidate
  f32x16 aH = zero16();
#pragma unroll
  for (int ks = 0; ks < 8; ++ks) {
    bf16x8 af = (ks < 4) ? xa[ks] : xr[ks - 4];
    aH = mm(af, LDWP(32, ks, wv), aH);
  }
  __syncthreads();  // xr reads done before tlds overwrite
  const float bh_ = bh[32 * wv + r31];
#pragma unroll
  for (int reg = 0; reg < 16; ++reg) {
    int row = (reg & 3) + 8 * (reg >> 2) + 4 * h;
    float hh = tanh_fast(aH[reg] + bh_);
    float z = zv[reg];
    tlds[row][oc] = (1.f - z) * propv[reg] + z * hh;
  }
  __syncthreads();
  bf16x8 xn[4];
#pragma unroll
  for (int ks = 0; ks < 4; ++ks) {
    float4 t0 = *reinterpret_cast<const float4*>(&tlds[r31][16 * ks + 8 * h]);
    float4 t1 = *reinterpret_cast<const float4*>(&tlds[r31][16 * ks + 8 * h + 4]);
    xn[ks] = cvt8(t0, t1);
  }
  // ---- stage 3: head
  f32x16 aO = zero16();
#pragma unroll
  for (int ks = 0; ks < 6; ++ks) {
    bf16x8 af = (ks < 4) ? xn[ks] : xan[ks - 4];
    aO = mm(af, LDWP(48, ks, wv), aO);
  }
  const float bo1_ = bo1[32 * wv + r31];
  const float wo2_ = Wo2[32 * wv + r31];
  const float bo2v = bo2[0];
  float pred[16];
#pragma unroll
  for (int reg = 0; reg < 16; ++reg) {
    float p = tanh_fast(aO[reg] + bo1_) * wo2_;
#pragma unroll
    for (int mks = 16; mks >= 1; mks >>= 1) p += __shfl_xor(p, mks, 64);
    pred[reg] = p;  // valid at r31==0 lanes (l==0 and l==32)
  }
  if (wv == 1 && r31 == 0) {
#pragma unroll
    for (int reg = 0; reg < 16; ++reg) sred[reg * 2 + h] = pred[reg];
  }
  __syncthreads();
  if (wv == 0 && r31 == 0) {
#pragma unroll
    for (int reg = 0; reg < 16; ++reg) {
      int row = (reg & 3) + 8 * (reg >> 2) + 4 * h;
      out[R0 + row] = pred[reg] + sred[reg * 2 + h] + bo2v;
    }
  }
#undef LDWP
}

extern "C" void kernel_launch(void* const* d_in, const int* in_sizes, int n_in,
                              void* d_out, int out_size, void* d_ws, size_t ws_size,
                              hipStream_t stream) {
  const float* prop  = (const float*)d_in[0];
  const float* annot = (const float*)d_in[1];
  const float* A     = (const float*)d_in[2];
  const float* Win   = (const float*)d_in[3];
  const float* bin   = (const float*)d_in[4];
  const float* Wr    = (const float*)d_in[5];
  const float* br    = (const float*)d_in[6];
  const float* Wz    = (const float*)d_in[7];
  const float* bz    = (const float*)d_in[8];
  const float* Wh    = (const float*)d_in[9];
  const float* bh    = (const float*)d_in[10];
  const float* Wo1   = (const float*)d_in[11];
  const float* bo1   = (const float*)d_in[12];
  const float* Wo2   = (const float*)d_in[13];
  const float* bo2   = (const float*)d_in[14];
  float* out = (float*)d_out;

  char* ws = (char*)d_ws;
  __bf16* Bt   = (__bf16*)ws;                              // [2][64][16384] bf16 = 4 MB
  __bf16* part = (__bf16*)(ws + (size_t)4 * 1024 * 1024);  // [256][8][32][64] bf16 = 8 MB
  __bf16* Wp   = (__bf16*)(ws + (size_t)16 * 1024 * 1024); // 60 KB

  k_packbt<<<dim3(513), 256, 0, stream>>>(prop, Win, bin, Bt,
                                          Wr, Wz, Wh, Wo1, Wp);
  k_big_gemm<<<dim3(256), 512, 0, stream>>>(A, Bt, part);
  k_gru<<<dim3(NT), 128, 0, stream>>>(part, prop, annot, Wp,
                                      br, bz, bh, bo1, Wo2, bo2, out);
}